// Round 6
// baseline (518.541 us; speedup 1.0000x reference)
//
#include <hip/hip_runtime.h>
#include <math.h>

#define N_NODES 50000
#define N_EDGES 800000
#define D 128

typedef __attribute__((ext_vector_type(8))) short bf16x8;
typedef __attribute__((ext_vector_type(4))) float f32x4;

static __device__ __forceinline__ unsigned short f2bf(float f) {
    unsigned int u = __float_as_uint(f);
    u = (u + 0x7fffu + ((u >> 16) & 1u)) >> 16;
    return (unsigned short)u;
}
static __device__ __forceinline__ float bf2f(unsigned short h) {
    return __uint_as_float(((unsigned int)h) << 16);
}

// ---------------- split x into hi/lo bf16 planes ----------------
__global__ void split_x_kernel(const float* __restrict__ in,
                               unsigned short* __restrict__ hi,
                               unsigned short* __restrict__ lo, int n) {
    int i = (blockIdx.x * blockDim.x + threadIdx.x) * 4;
    if (i < n) {
        float4 v = *(const float4*)(in + i);
        ushort4 h, l;
        h.x = f2bf(v.x); l.x = f2bf(v.x - bf2f(h.x));
        h.y = f2bf(v.y); l.y = f2bf(v.y - bf2f(h.y));
        h.z = f2bf(v.z); l.z = f2bf(v.z - bf2f(h.z));
        h.w = f2bf(v.w); l.w = f2bf(v.w - bf2f(h.w));
        *(ushort4*)(hi + i) = h;
        *(ushort4*)(lo + i) = l;
    }
}

// ---------------- weight split-cast: [F,128]+[F,128] -> hi/lo [F,256] ----------------
__global__ void cast_cat_kernel(const float* __restrict__ A, const float* __restrict__ B,
                                unsigned short* __restrict__ hi, unsigned short* __restrict__ lo) {
    int f = blockIdx.x, t = threadIdx.x;           // grid=128, block=128
    float va = A[f * 128 + t], vb = B[f * 128 + t];
    unsigned short ha = f2bf(va), hb = f2bf(vb);
    hi[f * 256 + t]       = ha;
    hi[f * 256 + 128 + t] = hb;
    lo[f * 256 + t]       = f2bf(va - bf2f(ha));
    lo[f * 256 + 128 + t] = f2bf(vb - bf2f(hb));
}

// W_lin [40,256] -> hi/lo [48,256] zero-padded. grid=48, block=256
__global__ void cast_wlin_kernel(const float* __restrict__ W,
                                 unsigned short* __restrict__ hi, unsigned short* __restrict__ lo) {
    int f = blockIdx.x, t = threadIdx.x;
    float v = (f < 40) ? W[f * 256 + t] : 0.f;
    unsigned short h = f2bf(v);
    hi[f * 256 + t] = h;
    lo[f * 256 + t] = f2bf(v - bf2f(h));
}

// ---------------- degree histogram (int) ----------------
__global__ void deg_kernel(const int* __restrict__ dst, int* __restrict__ deg) {
    int e = blockIdx.x * blockDim.x + threadIdx.x;
    if (e < N_EDGES) atomicAdd(&deg[dst[e]], 1);
}

// ---------------- single-block prefix sum ----------------
__global__ __launch_bounds__(1024) void scan_kernel(const int* __restrict__ deg,
                                                    int* __restrict__ rowptr,
                                                    int* __restrict__ cursor) {
    __shared__ int wtot[16];
    __shared__ int s_carry;
    int tid = threadIdx.x;
    int lane = tid & 63, wv = tid >> 6;
    if (tid == 0) s_carry = 0;
    __syncthreads();
    for (int base = 0; base < N_NODES; base += 1024) {
        int idx = base + tid;
        int v = (idx < N_NODES) ? deg[idx] : 0;
        int scan = v;
        #pragma unroll
        for (int o = 1; o < 64; o <<= 1) {
            int t = __shfl_up(scan, o, 64);
            if (lane >= o) scan += t;
        }
        if (lane == 63) wtot[wv] = scan;
        __syncthreads();
        int woff = 0;
        #pragma unroll
        for (int w = 0; w < 16; w++) woff += (w < wv) ? wtot[w] : 0;
        int carry = s_carry;
        int excl = carry + woff + scan - v;
        if (idx < N_NODES) { rowptr[idx] = excl; cursor[idx] = excl; }
        __syncthreads();
        if (tid == 0) {
            int tot = 0;
            #pragma unroll
            for (int w = 0; w < 16; w++) tot += wtot[w];
            s_carry = carry + tot;
        }
        __syncthreads();
    }
    if (tid == 0) rowptr[N_NODES] = s_carry;
}

// ---------------- bucket edges by dst ----------------
__global__ void bucket_kernel(const int* __restrict__ src, const int* __restrict__ dst,
                              int* __restrict__ cursor, int* __restrict__ srcs_sorted) {
    int e = blockIdx.x * blockDim.x + threadIdx.x;
    if (e < N_EDGES) {
        int pos = atomicAdd(&cursor[dst[e]], 1);
        srcs_sorted[pos] = src[e];
    }
}

// ---------------- gather epilogue: write hi/lo planes ----------------
static __device__ __forceinline__ void write_planes(unsigned short* __restrict__ ohi,
                                                    unsigned short* __restrict__ olo,
                                                    int node, int lane, float rx, float ry) {
    unsigned short h0 = f2bf(rx), h1 = f2bf(ry);
    unsigned short l0 = f2bf(rx - bf2f(h0)), l1 = f2bf(ry - bf2f(h1));
    ((unsigned int*)ohi)[(size_t)node * 64 + lane] = (unsigned int)h0 | ((unsigned int)h1 << 16);
    ((unsigned int*)olo)[(size_t)node * 64 + lane] = (unsigned int)l0 | ((unsigned int)l1 << 16);
}

// ---------------- CSR gather + mean from fp32 src (layer 1) ----------------
__global__ __launch_bounds__(256) void gather_mean_f32(const int* __restrict__ srcs,
                                                       const int* __restrict__ rowptr,
                                                       const float* __restrict__ x,
                                                       unsigned short* __restrict__ ohi,
                                                       unsigned short* __restrict__ olo) {
    int node = blockIdx.x * 4 + (threadIdx.x >> 6);
    if (node >= N_NODES) return;
    int lane = threadIdx.x & 63;
    int beg = rowptr[node], end = rowptr[node + 1];
    float2 a0 = {0.f, 0.f}, a1 = {0.f, 0.f}, a2 = {0.f, 0.f}, a3 = {0.f, 0.f};
    int i = beg;
    for (; i + 4 <= end; i += 4) {
        int s0 = srcs[i], s1 = srcs[i + 1], s2 = srcs[i + 2], s3 = srcs[i + 3];
        float2 v0 = *(const float2*)(x + (size_t)s0 * D + lane * 2);
        float2 v1 = *(const float2*)(x + (size_t)s1 * D + lane * 2);
        float2 v2 = *(const float2*)(x + (size_t)s2 * D + lane * 2);
        float2 v3 = *(const float2*)(x + (size_t)s3 * D + lane * 2);
        a0.x += v0.x; a0.y += v0.y;
        a1.x += v1.x; a1.y += v1.y;
        a2.x += v2.x; a2.y += v2.y;
        a3.x += v3.x; a3.y += v3.y;
    }
    for (; i < end; i++) {
        float2 v = *(const float2*)(x + (size_t)srcs[i] * D + lane * 2);
        a0.x += v.x; a0.y += v.y;
    }
    float inv = 1.0f / fmaxf((float)(end - beg), 1.0f);
    float rx = ((a0.x + a1.x) + (a2.x + a3.x)) * inv;
    float ry = ((a0.y + a1.y) + (a2.y + a3.y)) * inv;
    write_planes(ohi, olo, node, lane, rx, ry);
}

// ---------------- CSR gather + mean from hi/lo plane src (layer 2) ----------------
__global__ __launch_bounds__(256) void gather_mean_pl(const int* __restrict__ srcs,
                                                      const int* __restrict__ rowptr,
                                                      const unsigned short* __restrict__ shi,
                                                      const unsigned short* __restrict__ slo,
                                                      unsigned short* __restrict__ ohi,
                                                      unsigned short* __restrict__ olo) {
    int node = blockIdx.x * 4 + (threadIdx.x >> 6);
    if (node >= N_NODES) return;
    int lane = threadIdx.x & 63;
    int beg = rowptr[node], end = rowptr[node + 1];
    const unsigned int* hip_ = (const unsigned int*)shi;
    const unsigned int* lop_ = (const unsigned int*)slo;
    float2 a0 = {0.f, 0.f}, a1 = {0.f, 0.f};
    #define ACC_PL(s, acc) { \
        unsigned int uh = hip_[(size_t)(s) * 64 + lane]; \
        unsigned int ul = lop_[(size_t)(s) * 64 + lane]; \
        acc.x += __uint_as_float(uh << 16) + __uint_as_float(ul << 16); \
        acc.y += __uint_as_float(uh & 0xffff0000u) + __uint_as_float(ul & 0xffff0000u); }
    int i = beg;
    for (; i + 2 <= end; i += 2) {
        int s0 = srcs[i], s1 = srcs[i + 1];
        ACC_PL(s0, a0) ACC_PL(s1, a1)
    }
    for (; i < end; i++) { int s = srcs[i]; ACC_PL(s, a0) }
    #undef ACC_PL
    float inv = 1.0f / fmaxf((float)(end - beg), 1.0f);
    float rx = (a0.x + a1.x) * inv;
    float ry = (a0.y + a1.y) * inv;
    write_planes(ohi, olo, node, lane, rx, ry);
}

// ---------------- B-stationary split-bf16 MFMA layer GEMM ----------------
// Block = one f-tile (16 f) x 256 nodes; 4 waves each own a 64-node band.
// bh kept in regs, bl re-read (L1-resident, 16KB/block working set).
// grid = dim3(ceil(N/256), 8). out = relu(...) written as hi/lo planes.
__global__ __launch_bounds__(256) void mfma_layer_bs(
    const unsigned short* __restrict__ A1hi, const unsigned short* __restrict__ A1lo,
    const unsigned short* __restrict__ A2hi, const unsigned short* __restrict__ A2lo,
    const unsigned short* __restrict__ Whi, const unsigned short* __restrict__ Wlo,
    const float* __restrict__ bias,
    unsigned short* __restrict__ Ohi, unsigned short* __restrict__ Olo)
{
    int w = threadIdx.x >> 6, lane = threadIdx.x & 63;
    int m = lane & 15, quad = lane >> 4;
    int band0 = blockIdx.x * 256 + w * 64;
    int f = blockIdx.y * 16 + m;
    if (band0 >= N_NODES) return;

    bf16x8 bh[8];
    const unsigned short* whirow = Whi + (size_t)f * 256 + quad * 8;
    const unsigned short* wlorow = Wlo + (size_t)f * 256 + quad * 8;
    #pragma unroll
    for (int ks = 0; ks < 8; ks++) bh[ks] = *(const bf16x8*)(whirow + ks * 32);
    float bv = bias[f];

    #pragma unroll
    for (int t = 0; t < 4; t++) {
        int node = band0 + t * 16 + m;
        int nodec = min(node, N_NODES - 1);
        bf16x8 ahi[8], alo[8];
        {
            const unsigned short* r1h = A1hi + (size_t)nodec * D + quad * 8;
            const unsigned short* r1l = A1lo + (size_t)nodec * D + quad * 8;
            const unsigned short* r2h = A2hi + (size_t)nodec * D + quad * 8;
            const unsigned short* r2l = A2lo + (size_t)nodec * D + quad * 8;
            #pragma unroll
            for (int ks = 0; ks < 4; ks++) {
                ahi[ks]     = *(const bf16x8*)(r1h + ks * 32);
                alo[ks]     = *(const bf16x8*)(r1l + ks * 32);
                ahi[4 + ks] = *(const bf16x8*)(r2h + ks * 32);
                alo[4 + ks] = *(const bf16x8*)(r2l + ks * 32);
            }
        }
        f32x4 acc = {0.f, 0.f, 0.f, 0.f};
        #pragma unroll
        for (int ks = 0; ks < 8; ks++) {
            bf16x8 bl = *(const bf16x8*)(wlorow + ks * 32);
            acc = __builtin_amdgcn_mfma_f32_16x16x32_bf16(ahi[ks], bh[ks], acc, 0, 0, 0);
            acc = __builtin_amdgcn_mfma_f32_16x16x32_bf16(ahi[ks], bl,     acc, 0, 0, 0);
            acc = __builtin_amdgcn_mfma_f32_16x16x32_bf16(alo[ks], bh[ks], acc, 0, 0, 0);
        }
        #pragma unroll
        for (int r = 0; r < 4; r++) {
            int nrow = band0 + t * 16 + quad * 4 + r;
            if (nrow >= N_NODES) continue;
            float v = fmaxf(acc[r] + bv, 0.f);
            unsigned short h = f2bf(v);
            Ohi[(size_t)nrow * D + f] = h;
            Olo[(size_t)nrow * D + f] = f2bf(v - bf2f(h));
        }
    }
}

// ---------------- final GEMM (F=40, padded 48) + fused log_softmax ----------------
__global__ __launch_bounds__(256) void mfma_final_p(
    const unsigned short* __restrict__ M1hi, const unsigned short* __restrict__ M1lo,
    const unsigned short* __restrict__ M2hi, const unsigned short* __restrict__ M2lo,
    const unsigned short* __restrict__ Whi, const unsigned short* __restrict__ Wlo,
    const float* __restrict__ bias, float* __restrict__ out)
{
    int wave = threadIdx.x >> 6, lane = threadIdx.x & 63;
    int m = lane & 15, quad = lane >> 4;
    int node_base = (blockIdx.x * 4 + wave) * 16;
    if (node_base >= N_NODES) return;
    int nodec = min(node_base + m, N_NODES - 1);

    bf16x8 ahi[8], alo[8];
    {
        const unsigned short* r1h = M1hi + (size_t)nodec * D + quad * 8;
        const unsigned short* r1l = M1lo + (size_t)nodec * D + quad * 8;
        const unsigned short* r2h = M2hi + (size_t)nodec * D + quad * 8;
        const unsigned short* r2l = M2lo + (size_t)nodec * D + quad * 8;
        #pragma unroll
        for (int ks = 0; ks < 4; ks++) {
            ahi[ks]     = *(const bf16x8*)(r1h + ks * 32);
            alo[ks]     = *(const bf16x8*)(r1l + ks * 32);
            ahi[4 + ks] = *(const bf16x8*)(r2h + ks * 32);
            alo[4 + ks] = *(const bf16x8*)(r2l + ks * 32);
        }
    }

    float res[3][4];
    #pragma unroll
    for (int nt = 0; nt < 3; nt++) {
        int f = nt * 16 + m;
        const unsigned short* whirow = Whi + (size_t)f * 256 + quad * 8;
        const unsigned short* wlorow = Wlo + (size_t)f * 256 + quad * 8;
        f32x4 acc = {0.f, 0.f, 0.f, 0.f};
        #pragma unroll
        for (int ks = 0; ks < 8; ks++) {
            bf16x8 bh = *(const bf16x8*)(whirow + ks * 32);
            bf16x8 bl = *(const bf16x8*)(wlorow + ks * 32);
            acc = __builtin_amdgcn_mfma_f32_16x16x32_bf16(ahi[ks], bh, acc, 0, 0, 0);
            acc = __builtin_amdgcn_mfma_f32_16x16x32_bf16(ahi[ks], bl, acc, 0, 0, 0);
            acc = __builtin_amdgcn_mfma_f32_16x16x32_bf16(alo[ks], bh, acc, 0, 0, 0);
        }
        float bv = (f < 40) ? bias[f] : 0.f;
        #pragma unroll
        for (int r = 0; r < 4; r++) res[nt][r] = acc[r] + bv;
    }

    #pragma unroll
    for (int r = 0; r < 4; r++) {
        float pm = -INFINITY;
        #pragma unroll
        for (int nt = 0; nt < 3; nt++)
            if (nt * 16 + m < 40) pm = fmaxf(pm, res[nt][r]);
        #pragma unroll
        for (int o = 8; o > 0; o >>= 1) pm = fmaxf(pm, __shfl_xor(pm, o, 64));
        float ps = 0.f;
        #pragma unroll
        for (int nt = 0; nt < 3; nt++)
            if (nt * 16 + m < 40) ps += expf(res[nt][r] - pm);
        #pragma unroll
        for (int o = 8; o > 0; o >>= 1) ps += __shfl_xor(ps, o, 64);
        float lse = pm + logf(ps);
        int nrow = node_base + quad * 4 + r;
        if (nrow >= N_NODES) continue;
        #pragma unroll
        for (int nt = 0; nt < 3; nt++) {
            int f = nt * 16 + m;
            if (f < 40) out[(size_t)nrow * 40 + f] = res[nt][r] - lse;
        }
    }
}

extern "C" void kernel_launch(void* const* d_in, const int* in_sizes, int n_in,
                              void* d_out, int out_size, void* d_ws, size_t ws_size,
                              hipStream_t stream) {
    const float* x     = (const float*)d_in[0];
    const int*   ei    = (const int*)d_in[1];
    const int*   src   = ei;
    const int*   dst   = ei + N_EDGES;
    const float* W1_l  = (const float*)d_in[2];
    const float* b1_l  = (const float*)d_in[3];
    const float* W1_r  = (const float*)d_in[4];
    const float* W2_l  = (const float*)d_in[5];
    const float* b2_l  = (const float*)d_in[6];
    const float* W2_r  = (const float*)d_in[7];
    const float* W_lin = (const float*)d_in[8];
    const float* b_lin = (const float*)d_in[9];
    float* out = (float*)d_out;

    const size_t nd = (size_t)N_NODES * D;
    unsigned short* agghi = (unsigned short*)d_ws;   // 6 bf16 planes of nd elements
    unsigned short* agglo = agghi + nd;
    unsigned short* h1hi  = agglo + nd;
    unsigned short* h1lo  = h1hi + nd;
    unsigned short* h2hi  = h1lo + nd;               // doubles as x_hi before gemm2
    unsigned short* h2lo  = h2hi + nd;               // doubles as x_lo before gemm2
    unsigned short* xhi = h2hi, *xlo = h2lo;
    unsigned short* W1hi = h2lo + nd;                // 128*256 bf16 each
    unsigned short* W1lo = W1hi + 128 * 256;
    unsigned short* W2hi = W1lo + 128 * 256;
    unsigned short* W2lo = W2hi + 128 * 256;
    unsigned short* WLhi = W2lo + 128 * 256;         // 48*256
    unsigned short* WLlo = WLhi + 48 * 256;
    int* deg    = (int*)(WLlo + 48 * 256);
    int* rowptr = deg + N_NODES;
    int* cursor = rowptr + N_NODES + 1;
    int* srcs_sorted = cursor + N_NODES;

    // ---- CSR build (reused by both layers) ----
    hipMemsetAsync(deg, 0, N_NODES * sizeof(int), stream);
    deg_kernel<<<(N_EDGES + 255) / 256, 256, 0, stream>>>(dst, deg);
    scan_kernel<<<1, 1024, 0, stream>>>(deg, rowptr, cursor);
    bucket_kernel<<<(N_EDGES + 255) / 256, 256, 0, stream>>>(src, dst, cursor, srcs_sorted);

    // ---- casts / splits ----
    split_x_kernel<<<(N_NODES * D / 4 + 255) / 256, 256, 0, stream>>>(x, xhi, xlo, N_NODES * D);
    cast_cat_kernel<<<128, 128, 0, stream>>>(W1_l, W1_r, W1hi, W1lo);
    cast_cat_kernel<<<128, 128, 0, stream>>>(W2_l, W2_r, W2hi, W2lo);
    cast_wlin_kernel<<<48, 256, 0, stream>>>(W_lin, WLhi, WLlo);

    const dim3 lgrid((N_NODES + 255) / 256, 8);   // B-stationary layer GEMM
    const int fblk = (N_NODES + 63) / 64;         // final GEMM
    const int gblk = (N_NODES + 3) / 4;           // gathers

    // ---- layer 1 ----
    gather_mean_f32<<<gblk, 256, 0, stream>>>(srcs_sorted, rowptr, x, agghi, agglo);
    mfma_layer_bs<<<lgrid, 256, 0, stream>>>(agghi, agglo, xhi, xlo, W1hi, W1lo, b1_l, h1hi, h1lo);

    // ---- layer 2 (gemm2 overwrites x planes with h2 — x is dead by then) ----
    gather_mean_pl<<<gblk, 256, 0, stream>>>(srcs_sorted, rowptr, h1hi, h1lo, agghi, agglo);
    mfma_layer_bs<<<lgrid, 256, 0, stream>>>(agghi, agglo, h1hi, h1lo, W2hi, W2lo, b2_l, h2hi, h2lo);

    // ---- final linear + fused log_softmax ----
    mfma_final_p<<<fblk, 256, 0, stream>>>(h1hi, h1lo, h2hi, h2lo, WLhi, WLlo, b_lin, out);
}

// Round 7
// 436.258 us; speedup vs baseline: 1.1886x; 1.1886x over previous
//
#include <hip/hip_runtime.h>
#include <math.h>

#define N_NODES 50000
#define N_EDGES 800000
#define D 128

typedef __attribute__((ext_vector_type(8))) short bf16x8;
typedef __attribute__((ext_vector_type(4))) float f32x4;

static __device__ __forceinline__ unsigned short f2bf(float f) {
    unsigned int u = __float_as_uint(f);
    u = (u + 0x7fffu + ((u >> 16) & 1u)) >> 16;
    return (unsigned short)u;
}
static __device__ __forceinline__ float bf2f(unsigned short h) {
    return __uint_as_float(((unsigned int)h) << 16);
}

// ---------------- split x into hi/lo bf16 planes ----------------
__global__ void split_x_kernel(const float* __restrict__ in,
                               unsigned short* __restrict__ hi,
                               unsigned short* __restrict__ lo, int n) {
    int i = (blockIdx.x * blockDim.x + threadIdx.x) * 4;
    if (i < n) {
        float4 v = *(const float4*)(in + i);
        ushort4 h, l;
        h.x = f2bf(v.x); l.x = f2bf(v.x - bf2f(h.x));
        h.y = f2bf(v.y); l.y = f2bf(v.y - bf2f(h.y));
        h.z = f2bf(v.z); l.z = f2bf(v.z - bf2f(h.z));
        h.w = f2bf(v.w); l.w = f2bf(v.w - bf2f(h.w));
        *(ushort4*)(hi + i) = h;
        *(ushort4*)(lo + i) = l;
    }
}

// ---------------- weight split-cast: [F,128]+[F,128] -> hi/lo [F,256] ----------------
__global__ void cast_cat_kernel(const float* __restrict__ A, const float* __restrict__ B,
                                unsigned short* __restrict__ hi, unsigned short* __restrict__ lo) {
    int f = blockIdx.x, t = threadIdx.x;           // grid=128, block=128
    float va = A[f * 128 + t], vb = B[f * 128 + t];
    unsigned short ha = f2bf(va), hb = f2bf(vb);
    hi[f * 256 + t]       = ha;
    hi[f * 256 + 128 + t] = hb;
    lo[f * 256 + t]       = f2bf(va - bf2f(ha));
    lo[f * 256 + 128 + t] = f2bf(vb - bf2f(hb));
}

// W_lin [40,256] -> hi/lo [48,256] zero-padded. grid=48, block=256
__global__ void cast_wlin_kernel(const float* __restrict__ W,
                                 unsigned short* __restrict__ hi, unsigned short* __restrict__ lo) {
    int f = blockIdx.x, t = threadIdx.x;
    float v = (f < 40) ? W[f * 256 + t] : 0.f;
    unsigned short h = f2bf(v);
    hi[f * 256 + t] = h;
    lo[f * 256 + t] = f2bf(v - bf2f(h));
}

// ---------------- degree histogram (int) ----------------
__global__ void deg_kernel(const int* __restrict__ dst, int* __restrict__ deg) {
    int e = blockIdx.x * blockDim.x + threadIdx.x;
    if (e < N_EDGES) atomicAdd(&deg[dst[e]], 1);
}

// ---------------- single-block prefix sum ----------------
__global__ __launch_bounds__(1024) void scan_kernel(const int* __restrict__ deg,
                                                    int* __restrict__ rowptr,
                                                    int* __restrict__ cursor) {
    __shared__ int wtot[16];
    __shared__ int s_carry;
    int tid = threadIdx.x;
    int lane = tid & 63, wv = tid >> 6;
    if (tid == 0) s_carry = 0;
    __syncthreads();
    for (int base = 0; base < N_NODES; base += 1024) {
        int idx = base + tid;
        int v = (idx < N_NODES) ? deg[idx] : 0;
        int scan = v;
        #pragma unroll
        for (int o = 1; o < 64; o <<= 1) {
            int t = __shfl_up(scan, o, 64);
            if (lane >= o) scan += t;
        }
        if (lane == 63) wtot[wv] = scan;
        __syncthreads();
        int woff = 0;
        #pragma unroll
        for (int w = 0; w < 16; w++) woff += (w < wv) ? wtot[w] : 0;
        int carry = s_carry;
        int excl = carry + woff + scan - v;
        if (idx < N_NODES) { rowptr[idx] = excl; cursor[idx] = excl; }
        __syncthreads();
        if (tid == 0) {
            int tot = 0;
            #pragma unroll
            for (int w = 0; w < 16; w++) tot += wtot[w];
            s_carry = carry + tot;
        }
        __syncthreads();
    }
    if (tid == 0) rowptr[N_NODES] = s_carry;
}

// ---------------- bucket edges by dst ----------------
__global__ void bucket_kernel(const int* __restrict__ src, const int* __restrict__ dst,
                              int* __restrict__ cursor, int* __restrict__ srcs_sorted) {
    int e = blockIdx.x * blockDim.x + threadIdx.x;
    if (e < N_EDGES) {
        int pos = atomicAdd(&cursor[dst[e]], 1);
        srcs_sorted[pos] = src[e];
    }
}

// ---------------- gather epilogue: write hi/lo planes ----------------
static __device__ __forceinline__ void write_planes(unsigned short* __restrict__ ohi,
                                                    unsigned short* __restrict__ olo,
                                                    int node, int lane, float rx, float ry) {
    unsigned short h0 = f2bf(rx), h1 = f2bf(ry);
    unsigned short l0 = f2bf(rx - bf2f(h0)), l1 = f2bf(ry - bf2f(h1));
    ((unsigned int*)ohi)[(size_t)node * 64 + lane] = (unsigned int)h0 | ((unsigned int)h1 << 16);
    ((unsigned int*)olo)[(size_t)node * 64 + lane] = (unsigned int)l0 | ((unsigned int)l1 << 16);
}

// ---------------- CSR gather + mean from hi plane (2B/elem), 8-deep MLP ----------------
__global__ __launch_bounds__(256) void gather_mean_hi(const int* __restrict__ srcs,
                                                      const int* __restrict__ rowptr,
                                                      const unsigned short* __restrict__ shi,
                                                      unsigned short* __restrict__ ohi,
                                                      unsigned short* __restrict__ olo) {
    int node = blockIdx.x * 4 + (threadIdx.x >> 6);
    if (node >= N_NODES) return;
    int lane = threadIdx.x & 63;
    int beg = rowptr[node], end = rowptr[node + 1];
    const unsigned int* xp = (const unsigned int*)shi;   // row = 64 dwords (128 bf16)
    float ax[8] = {0,0,0,0,0,0,0,0}, ay[8] = {0,0,0,0,0,0,0,0};
    int i = beg;
    for (; i + 8 <= end; i += 8) {
        unsigned int u[8];
        #pragma unroll
        for (int j = 0; j < 8; j++) u[j] = xp[(size_t)srcs[i + j] * 64 + lane];
        #pragma unroll
        for (int j = 0; j < 8; j++) {
            ax[j] += __uint_as_float(u[j] << 16);
            ay[j] += __uint_as_float(u[j] & 0xffff0000u);
        }
    }
    for (; i < end; i++) {
        unsigned int u = xp[(size_t)srcs[i] * 64 + lane];
        ax[0] += __uint_as_float(u << 16);
        ay[0] += __uint_as_float(u & 0xffff0000u);
    }
    float sx = ((ax[0] + ax[1]) + (ax[2] + ax[3])) + ((ax[4] + ax[5]) + (ax[6] + ax[7]));
    float sy = ((ay[0] + ay[1]) + (ay[2] + ay[3])) + ((ay[4] + ay[5]) + (ay[6] + ay[7]));
    float inv = 1.0f / fmaxf((float)(end - beg), 1.0f);
    write_planes(ohi, olo, node, lane, sx * inv, sy * inv);
}

// ---------------- layer GEMM: LDS-staged Whi, global Wlo, up-front A loads ----------------
// Grid (ceil(N/64), 2). Block 256 = 4 waves; wave = 16 nodes x 4 f-tiles (f-half of 64).
// out[n,f] = relu([A1|A2][n,:] . W[f,:] + bias[f]) written as hi/lo planes.
__global__ __launch_bounds__(256) void mfma_layer(
    const unsigned short* __restrict__ A1hi, const unsigned short* __restrict__ A1lo,
    const unsigned short* __restrict__ A2hi, const unsigned short* __restrict__ A2lo,
    const unsigned short* __restrict__ Whi, const unsigned short* __restrict__ Wlo,
    const float* __restrict__ bias,
    unsigned short* __restrict__ Ohi, unsigned short* __restrict__ Olo)
{
    // permuted Whi tile: chunk c = (nt*8+ks)*64 + (m*4+quad), 16B each; 2048 chunks = 32 KB
    __shared__ unsigned short lds[16384];
    const int tid = threadIdx.x;
    const int f0 = blockIdx.y * 64;

    #pragma unroll
    for (int it = 0; it < 8; it++) {
        int c = tid + it * 256;
        int nt = c >> 9, w = c & 511;
        int ks = w >> 6, lidx = w & 63;
        int mm = lidx >> 2, qq = lidx & 3;
        const unsigned short* g = Whi + (size_t)(f0 + nt * 16 + mm) * 256 + ks * 32 + qq * 8;
        *(bf16x8*)&lds[c * 8] = *(const bf16x8*)g;
    }
    __syncthreads();

    int wv = tid >> 6, lane = tid & 63;
    int m = lane & 15, quad = lane >> 4;
    int node_base = (blockIdx.x * 4 + wv) * 16;
    if (node_base >= N_NODES) return;
    int nodec = min(node_base + m, N_NODES - 1);

    // all 32 A-frag loads issued up-front
    bf16x8 ahi[8], alo[8];
    {
        const unsigned short* r1h = A1hi + (size_t)nodec * D + quad * 8;
        const unsigned short* r1l = A1lo + (size_t)nodec * D + quad * 8;
        const unsigned short* r2h = A2hi + (size_t)nodec * D + quad * 8;
        const unsigned short* r2l = A2lo + (size_t)nodec * D + quad * 8;
        #pragma unroll
        for (int ks = 0; ks < 4; ks++) {
            ahi[ks]     = *(const bf16x8*)(r1h + ks * 32);
            ahi[4 + ks] = *(const bf16x8*)(r2h + ks * 32);
            alo[ks]     = *(const bf16x8*)(r1l + ks * 32);
            alo[4 + ks] = *(const bf16x8*)(r2l + ks * 32);
        }
    }

    #pragma unroll
    for (int nt = 0; nt < 4; nt++) {
        int f = f0 + nt * 16 + m;
        // Wlo fragments up-front (L2-resident 64 KB array)
        bf16x8 bl[8];
        const unsigned short* wlorow = Wlo + (size_t)f * 256 + quad * 8;
        #pragma unroll
        for (int ks = 0; ks < 8; ks++) bl[ks] = *(const bf16x8*)(wlorow + ks * 32);

        f32x4 acc = {0.f, 0.f, 0.f, 0.f};
        #pragma unroll
        for (int ks = 0; ks < 8; ks++) {
            bf16x8 bh = *(const bf16x8*)&lds[(((nt * 8 + ks) * 64) + (m * 4 + quad)) * 8];
            acc = __builtin_amdgcn_mfma_f32_16x16x32_bf16(ahi[ks], bh,     acc, 0, 0, 0);
            acc = __builtin_amdgcn_mfma_f32_16x16x32_bf16(ahi[ks], bl[ks], acc, 0, 0, 0);
            acc = __builtin_amdgcn_mfma_f32_16x16x32_bf16(alo[ks], bh,     acc, 0, 0, 0);
        }
        float bv = bias[f];
        #pragma unroll
        for (int r = 0; r < 4; r++) {
            int nrow = node_base + quad * 4 + r;
            if (nrow >= N_NODES) continue;
            float v = fmaxf(acc[r] + bv, 0.f);
            unsigned short h = f2bf(v);
            Ohi[(size_t)nrow * D + f] = h;
            Olo[(size_t)nrow * D + f] = f2bf(v - bf2f(h));
        }
    }
}

// ---------------- final GEMM (F=40, padded 48) + fused log_softmax ----------------
__global__ __launch_bounds__(256) void mfma_final_p(
    const unsigned short* __restrict__ M1hi, const unsigned short* __restrict__ M1lo,
    const unsigned short* __restrict__ M2hi, const unsigned short* __restrict__ M2lo,
    const unsigned short* __restrict__ Whi, const unsigned short* __restrict__ Wlo,
    const float* __restrict__ bias, float* __restrict__ out)
{
    int wave = threadIdx.x >> 6, lane = threadIdx.x & 63;
    int m = lane & 15, quad = lane >> 4;
    int node_base = (blockIdx.x * 4 + wave) * 16;
    if (node_base >= N_NODES) return;
    int nodec = min(node_base + m, N_NODES - 1);

    bf16x8 ahi[8], alo[8];
    {
        const unsigned short* r1h = M1hi + (size_t)nodec * D + quad * 8;
        const unsigned short* r1l = M1lo + (size_t)nodec * D + quad * 8;
        const unsigned short* r2h = M2hi + (size_t)nodec * D + quad * 8;
        const unsigned short* r2l = M2lo + (size_t)nodec * D + quad * 8;
        #pragma unroll
        for (int ks = 0; ks < 4; ks++) {
            ahi[ks]     = *(const bf16x8*)(r1h + ks * 32);
            ahi[4 + ks] = *(const bf16x8*)(r2h + ks * 32);
            alo[ks]     = *(const bf16x8*)(r1l + ks * 32);
            alo[4 + ks] = *(const bf16x8*)(r2l + ks * 32);
        }
    }

    float res[3][4];
    #pragma unroll
    for (int nt = 0; nt < 3; nt++) {
        int f = nt * 16 + m;
        const unsigned short* whirow = Whi + (size_t)f * 256 + quad * 8;
        const unsigned short* wlorow = Wlo + (size_t)f * 256 + quad * 8;
        bf16x8 bh[8], bl[8];
        #pragma unroll
        for (int ks = 0; ks < 8; ks++) {
            bh[ks] = *(const bf16x8*)(whirow + ks * 32);
            bl[ks] = *(const bf16x8*)(wlorow + ks * 32);
        }
        f32x4 acc = {0.f, 0.f, 0.f, 0.f};
        #pragma unroll
        for (int ks = 0; ks < 8; ks++) {
            acc = __builtin_amdgcn_mfma_f32_16x16x32_bf16(ahi[ks], bh[ks], acc, 0, 0, 0);
            acc = __builtin_amdgcn_mfma_f32_16x16x32_bf16(ahi[ks], bl[ks], acc, 0, 0, 0);
            acc = __builtin_amdgcn_mfma_f32_16x16x32_bf16(alo[ks], bh[ks], acc, 0, 0, 0);
        }
        float bv = (f < 40) ? bias[f] : 0.f;
        #pragma unroll
        for (int r = 0; r < 4; r++) res[nt][r] = acc[r] + bv;
    }

    #pragma unroll
    for (int r = 0; r < 4; r++) {
        float pm = -INFINITY;
        #pragma unroll
        for (int nt = 0; nt < 3; nt++)
            if (nt * 16 + m < 40) pm = fmaxf(pm, res[nt][r]);
        #pragma unroll
        for (int o = 8; o > 0; o >>= 1) pm = fmaxf(pm, __shfl_xor(pm, o, 64));
        float ps = 0.f;
        #pragma unroll
        for (int nt = 0; nt < 3; nt++)
            if (nt * 16 + m < 40) ps += expf(res[nt][r] - pm);
        #pragma unroll
        for (int o = 8; o > 0; o >>= 1) ps += __shfl_xor(ps, o, 64);
        float lse = pm + logf(ps);
        int nrow = node_base + quad * 4 + r;
        if (nrow >= N_NODES) continue;
        #pragma unroll
        for (int nt = 0; nt < 3; nt++) {
            int f = nt * 16 + m;
            if (f < 40) out[(size_t)nrow * 40 + f] = res[nt][r] - lse;
        }
    }
}

extern "C" void kernel_launch(void* const* d_in, const int* in_sizes, int n_in,
                              void* d_out, int out_size, void* d_ws, size_t ws_size,
                              hipStream_t stream) {
    const float* x     = (const float*)d_in[0];
    const int*   ei    = (const int*)d_in[1];
    const int*   src   = ei;
    const int*   dst   = ei + N_EDGES;
    const float* W1_l  = (const float*)d_in[2];
    const float* b1_l  = (const float*)d_in[3];
    const float* W1_r  = (const float*)d_in[4];
    const float* W2_l  = (const float*)d_in[5];
    const float* b2_l  = (const float*)d_in[6];
    const float* W2_r  = (const float*)d_in[7];
    const float* W_lin = (const float*)d_in[8];
    const float* b_lin = (const float*)d_in[9];
    float* out = (float*)d_out;

    const size_t nd = (size_t)N_NODES * D;
    unsigned short* agghi = (unsigned short*)d_ws;   // 6 bf16 planes of nd elements
    unsigned short* agglo = agghi + nd;
    unsigned short* h1hi  = agglo + nd;
    unsigned short* h1lo  = h1hi + nd;
    unsigned short* h2hi  = h1lo + nd;               // doubles as x_hi before gemm2
    unsigned short* h2lo  = h2hi + nd;               // doubles as x_lo before gemm2
    unsigned short* xhi = h2hi, *xlo = h2lo;
    unsigned short* W1hi = h2lo + nd;                // 128*256 bf16 each
    unsigned short* W1lo = W1hi + 128 * 256;
    unsigned short* W2hi = W1lo + 128 * 256;
    unsigned short* W2lo = W2hi + 128 * 256;
    unsigned short* WLhi = W2lo + 128 * 256;         // 48*256
    unsigned short* WLlo = WLhi + 48 * 256;
    int* deg    = (int*)(WLlo + 48 * 256);
    int* rowptr = deg + N_NODES;
    int* cursor = rowptr + N_NODES + 1;
    int* srcs_sorted = cursor + N_NODES;

    // ---- CSR build (reused by both layers) ----
    hipMemsetAsync(deg, 0, N_NODES * sizeof(int), stream);
    deg_kernel<<<(N_EDGES + 255) / 256, 256, 0, stream>>>(dst, deg);
    scan_kernel<<<1, 1024, 0, stream>>>(deg, rowptr, cursor);
    bucket_kernel<<<(N_EDGES + 255) / 256, 256, 0, stream>>>(src, dst, cursor, srcs_sorted);

    // ---- casts / splits ----
    split_x_kernel<<<(N_NODES * D / 4 + 255) / 256, 256, 0, stream>>>(x, xhi, xlo, N_NODES * D);
    cast_cat_kernel<<<128, 128, 0, stream>>>(W1_l, W1_r, W1hi, W1lo);
    cast_cat_kernel<<<128, 128, 0, stream>>>(W2_l, W2_r, W2hi, W2lo);
    cast_wlin_kernel<<<48, 256, 0, stream>>>(W_lin, WLhi, WLlo);

    const dim3 lgrid((N_NODES + 63) / 64, 2);     // layer GEMM: 64 nodes x 64 f per block
    const int fblk = (N_NODES + 63) / 64;         // final GEMM
    const int gblk = (N_NODES + 3) / 4;           // gathers

    // ---- layer 1 ----
    gather_mean_hi<<<gblk, 256, 0, stream>>>(srcs_sorted, rowptr, xhi, agghi, agglo);
    mfma_layer<<<lgrid, 256, 0, stream>>>(agghi, agglo, xhi, xlo, W1hi, W1lo, b1_l, h1hi, h1lo);

    // ---- layer 2 (gemm2 overwrites x planes with h2 — x is dead by then) ----
    gather_mean_hi<<<gblk, 256, 0, stream>>>(srcs_sorted, rowptr, h1hi, agghi, agglo);
    mfma_layer<<<lgrid, 256, 0, stream>>>(agghi, agglo, h1hi, h1lo, W2hi, W2lo, b2_l, h2hi, h2lo);

    // ---- final linear + fused log_softmax ----
    mfma_final_p<<<fblk, 256, 0, stream>>>(h1hi, h1lo, h2hi, h2lo, WLhi, WLlo, b_lin, out);
}

// Round 8
// 411.007 us; speedup vs baseline: 1.2616x; 1.0614x over previous
//
#include <hip/hip_runtime.h>
#include <math.h>

#define N_NODES 50000
#define N_EDGES 800000
#define D 128
#define NBLK 196   // ceil(N_NODES/256)

typedef __attribute__((ext_vector_type(8))) short bf16x8;
typedef __attribute__((ext_vector_type(4))) float f32x4;

static __device__ __forceinline__ unsigned short f2bf(float f) {
    unsigned int u = __float_as_uint(f);
    u = (u + 0x7fffu + ((u >> 16) & 1u)) >> 16;
    return (unsigned short)u;
}
static __device__ __forceinline__ float bf2f(unsigned short h) {
    return __uint_as_float(((unsigned int)h) << 16);
}

// ---------------- split x into hi/lo bf16 planes ----------------
__global__ void split_x_kernel(const float* __restrict__ in,
                               unsigned short* __restrict__ hi,
                               unsigned short* __restrict__ lo, int n) {
    int i = (blockIdx.x * blockDim.x + threadIdx.x) * 4;
    if (i < n) {
        float4 v = *(const float4*)(in + i);
        ushort4 h, l;
        h.x = f2bf(v.x); l.x = f2bf(v.x - bf2f(h.x));
        h.y = f2bf(v.y); l.y = f2bf(v.y - bf2f(h.y));
        h.z = f2bf(v.z); l.z = f2bf(v.z - bf2f(h.z));
        h.w = f2bf(v.w); l.w = f2bf(v.w - bf2f(h.w));
        *(ushort4*)(hi + i) = h;
        *(ushort4*)(lo + i) = l;
    }
}

// ---------------- weight split-cast: [F,128]+[F,128] -> hi/lo [F,256] ----------------
__global__ void cast_cat_kernel(const float* __restrict__ A, const float* __restrict__ B,
                                unsigned short* __restrict__ hi, unsigned short* __restrict__ lo) {
    int f = blockIdx.x, t = threadIdx.x;           // grid=128, block=128
    float va = A[f * 128 + t], vb = B[f * 128 + t];
    unsigned short ha = f2bf(va), hb = f2bf(vb);
    hi[f * 256 + t]       = ha;
    hi[f * 256 + 128 + t] = hb;
    lo[f * 256 + t]       = f2bf(va - bf2f(ha));
    lo[f * 256 + 128 + t] = f2bf(vb - bf2f(hb));
}

// W_lin [40,256] -> hi/lo [48,256] zero-padded. grid=48, block=256
__global__ void cast_wlin_kernel(const float* __restrict__ W,
                                 unsigned short* __restrict__ hi, unsigned short* __restrict__ lo) {
    int f = blockIdx.x, t = threadIdx.x;
    float v = (f < 40) ? W[f * 256 + t] : 0.f;
    unsigned short h = f2bf(v);
    hi[f * 256 + t] = h;
    lo[f * 256 + t] = f2bf(v - bf2f(h));
}

// ---------------- degree histogram (int) ----------------
__global__ void deg_kernel(const int* __restrict__ dst, int* __restrict__ deg) {
    int e = blockIdx.x * blockDim.x + threadIdx.x;
    if (e < N_EDGES) atomicAdd(&deg[dst[e]], 1);
}

// ---------------- parallel 3-stage scan ----------------
__global__ void scan_block_sums(const int* __restrict__ deg, int* __restrict__ bsum) {
    __shared__ int wt[4];
    int tid = threadIdx.x, lane = tid & 63, wv = tid >> 6;
    int idx = blockIdx.x * 256 + tid;
    int v = (idx < N_NODES) ? deg[idx] : 0;
    int s = v;
    #pragma unroll
    for (int o = 1; o < 64; o <<= 1) s += __shfl_xor(s, o, 64);
    if (lane == 0) wt[wv] = s;
    __syncthreads();
    if (tid == 0) bsum[blockIdx.x] = wt[0] + wt[1] + wt[2] + wt[3];
}

__global__ void scan_offsets(const int* __restrict__ bsum, int* __restrict__ boff) {
    __shared__ int wt[4];
    int tid = threadIdx.x, lane = tid & 63, wv = tid >> 6;
    int v = (tid < NBLK) ? bsum[tid] : 0;
    int s = v;
    #pragma unroll
    for (int o = 1; o < 64; o <<= 1) { int t = __shfl_up(s, o, 64); if (lane >= o) s += t; }
    if (lane == 63) wt[wv] = s;
    __syncthreads();
    int off = 0;
    #pragma unroll
    for (int w = 0; w < 4; w++) off += (w < wv) ? wt[w] : 0;
    if (tid < NBLK) boff[tid] = off + s - v;
}

__global__ void scan_write(const int* __restrict__ deg, const int* __restrict__ boff,
                           int* __restrict__ rowptr, int* __restrict__ cursor) {
    __shared__ int wt[4];
    int tid = threadIdx.x, lane = tid & 63, wv = tid >> 6;
    int idx = blockIdx.x * 256 + tid;
    int v = (idx < N_NODES) ? deg[idx] : 0;
    int s = v;
    #pragma unroll
    for (int o = 1; o < 64; o <<= 1) { int t = __shfl_up(s, o, 64); if (lane >= o) s += t; }
    if (lane == 63) wt[wv] = s;
    __syncthreads();
    int off = boff[blockIdx.x];
    #pragma unroll
    for (int w = 0; w < 4; w++) off += (w < wv) ? wt[w] : 0;
    int excl = off + s - v;
    if (idx < N_NODES) { rowptr[idx] = excl; cursor[idx] = excl; }
    if (idx == 0) rowptr[N_NODES] = N_EDGES;
}

// ---------------- bucket edges by dst ----------------
__global__ void bucket_kernel(const int* __restrict__ src, const int* __restrict__ dst,
                              int* __restrict__ cursor, int* __restrict__ srcs_sorted) {
    int e = blockIdx.x * blockDim.x + threadIdx.x;
    if (e < N_EDGES) {
        int pos = atomicAdd(&cursor[dst[e]], 1);
        srcs_sorted[pos] = src[e];
    }
}

// ---------------- fused layer: gather-mean (LDS) + split-bf16 MFMA GEMM ----------------
// Block = 512 threads (8 waves) = 64 nodes, all 128 outputs.
// Phase 1: 8 waves gather 8 nodes each into LDS (hi/lo split, 68-dword row stride).
// Phase 2: wave w -> node group (w&3)*16, f-pair (w>>2); Whi staged in LDS per 64-f half.
__global__ __launch_bounds__(512, 4) void fused_layer(
    const int* __restrict__ srcs, const int* __restrict__ rowptr,
    const unsigned short* __restrict__ Shi,                                     // gather source hi plane
    const unsigned short* __restrict__ A2hi, const unsigned short* __restrict__ A2lo,  // self planes
    const unsigned short* __restrict__ Whi, const unsigned short* __restrict__ Wlo,    // [128,256]
    const float* __restrict__ bias,
    unsigned short* __restrict__ Ohi, unsigned short* __restrict__ Olo)
{
    __shared__ unsigned int Ah[64 * 68];       // 17.4 KB
    __shared__ unsigned int Al[64 * 68];       // 17.4 KB
    __shared__ unsigned short Wl[16384];       // 32 KB

    const int tid = threadIdx.x;
    const int wv = tid >> 6, lane = tid & 63;
    const int nb0 = blockIdx.x * 64;

    // ---- phase 1: gather-mean into LDS ----
    const unsigned int* xp = (const unsigned int*)Shi;   // row = 64 dwords
    for (int it = 0; it < 8; it++) {
        int nl = it * 8 + wv;
        int node = min(nb0 + nl, N_NODES - 1);
        int beg = rowptr[node], end = rowptr[node + 1];
        float ax[8] = {0,0,0,0,0,0,0,0}, ay[8] = {0,0,0,0,0,0,0,0};
        int i = beg;
        for (; i + 16 <= end; i += 16) {
            unsigned int u[16];
            #pragma unroll
            for (int j = 0; j < 16; j++) u[j] = xp[(size_t)srcs[i + j] * 64 + lane];
            #pragma unroll
            for (int j = 0; j < 16; j++) {
                ax[j & 7] += __uint_as_float(u[j] << 16);
                ay[j & 7] += __uint_as_float(u[j] & 0xffff0000u);
            }
        }
        for (; i + 4 <= end; i += 4) {
            unsigned int u[4];
            #pragma unroll
            for (int j = 0; j < 4; j++) u[j] = xp[(size_t)srcs[i + j] * 64 + lane];
            #pragma unroll
            for (int j = 0; j < 4; j++) {
                ax[j] += __uint_as_float(u[j] << 16);
                ay[j] += __uint_as_float(u[j] & 0xffff0000u);
            }
        }
        for (; i < end; i++) {
            unsigned int u = xp[(size_t)srcs[i] * 64 + lane];
            ax[0] += __uint_as_float(u << 16);
            ay[0] += __uint_as_float(u & 0xffff0000u);
        }
        float sx = ((ax[0] + ax[1]) + (ax[2] + ax[3])) + ((ax[4] + ax[5]) + (ax[6] + ax[7]));
        float sy = ((ay[0] + ay[1]) + (ay[2] + ay[3])) + ((ay[4] + ay[5]) + (ay[6] + ay[7]));
        float inv = 1.0f / fmaxf((float)(end - beg), 1.0f);
        sx *= inv; sy *= inv;
        unsigned short h0 = f2bf(sx), h1 = f2bf(sy);
        unsigned short l0 = f2bf(sx - bf2f(h0)), l1 = f2bf(sy - bf2f(h1));
        Ah[nl * 68 + lane] = (unsigned int)h0 | ((unsigned int)h1 << 16);
        Al[nl * 68 + lane] = (unsigned int)l0 | ((unsigned int)l1 << 16);
    }
    __syncthreads();   // A tiles ready

    const int m = lane & 15, quad = lane >> 4;
    const int g = wv & 3, tp = wv >> 2;
    const int node_base = nb0 + g * 16;
    const int nodec = min(node_base + m, N_NODES - 1);

    // A1 frags (agg, K 0..127) from LDS; A2 frags (self, K 128..255) from global
    bf16x8 a1h[4], a1l[4], a2h[4], a2l[4];
    {
        const unsigned short* r2h = A2hi + (size_t)nodec * D + quad * 8;
        const unsigned short* r2l = A2lo + (size_t)nodec * D + quad * 8;
        #pragma unroll
        for (int ks = 0; ks < 4; ks++) {
            a2h[ks] = *(const bf16x8*)(r2h + ks * 32);
            a2l[ks] = *(const bf16x8*)(r2l + ks * 32);
        }
        #pragma unroll
        for (int ks = 0; ks < 4; ks++) {
            int ad = ((g * 16 + m) * 68 + quad * 4 + ks * 16) * 2;   // ushort offset
            a1h[ks] = *(const bf16x8*)((const unsigned short*)Ah + ad);
            a1l[ks] = *(const bf16x8*)((const unsigned short*)Al + ad);
        }
    }

    #pragma unroll 1
    for (int fh = 0; fh < 2; fh++) {
        const int f0 = fh * 64;
        if (fh) __syncthreads();     // protect Wl reuse
        // stage Whi half, permuted chunks: c = (nt*8+ks)*64 + (m*4+quad)
        #pragma unroll
        for (int itS = 0; itS < 4; itS++) {
            int c = tid + itS * 512;
            int nt = c >> 9, w2 = c & 511;
            int ks = w2 >> 6, lidx = w2 & 63;
            int mm = lidx >> 2, qq = lidx & 3;
            const unsigned short* gp = Whi + (size_t)(f0 + nt * 16 + mm) * 256 + ks * 32 + qq * 8;
            *(bf16x8*)&Wl[(size_t)c * 8] = *(const bf16x8*)gp;
        }
        __syncthreads();

        #pragma unroll
        for (int j = 0; j < 2; j++) {
            int ntl = tp * 2 + j;
            int f = f0 + ntl * 16 + m;
            const unsigned short* wlorow = Wlo + (size_t)f * 256 + quad * 8;
            f32x4 acc = {0.f, 0.f, 0.f, 0.f};
            #pragma unroll
            for (int ks = 0; ks < 8; ks++) {
                bf16x8 bh = *(const bf16x8*)&Wl[(size_t)(((ntl * 8 + ks) << 6) + (m * 4 + quad)) * 8];
                bf16x8 bl = *(const bf16x8*)(wlorow + ks * 32);
                bf16x8 ah = (ks < 4) ? a1h[ks] : a2h[ks - 4];
                bf16x8 al = (ks < 4) ? a1l[ks] : a2l[ks - 4];
                acc = __builtin_amdgcn_mfma_f32_16x16x32_bf16(ah, bh, acc, 0, 0, 0);
                acc = __builtin_amdgcn_mfma_f32_16x16x32_bf16(ah, bl, acc, 0, 0, 0);
                acc = __builtin_amdgcn_mfma_f32_16x16x32_bf16(al, bh, acc, 0, 0, 0);
            }
            float bv = bias[f];
            #pragma unroll
            for (int r = 0; r < 4; r++) {
                int nrow = node_base + quad * 4 + r;
                if (nrow >= N_NODES) continue;
                float v = fmaxf(acc[r] + bv, 0.f);
                unsigned short h = f2bf(v);
                Ohi[(size_t)nrow * D + f] = h;
                Olo[(size_t)nrow * D + f] = f2bf(v - bf2f(h));
            }
        }
    }
}

// ---------------- final GEMM (F=40, padded 48) + fused log_softmax ----------------
__global__ __launch_bounds__(256) void mfma_final_p(
    const unsigned short* __restrict__ M1hi, const unsigned short* __restrict__ M1lo,
    const unsigned short* __restrict__ M2hi, const unsigned short* __restrict__ M2lo,
    const unsigned short* __restrict__ Whi, const unsigned short* __restrict__ Wlo,
    const float* __restrict__ bias, float* __restrict__ out)
{
    int wave = threadIdx.x >> 6, lane = threadIdx.x & 63;
    int m = lane & 15, quad = lane >> 4;
    int node_base = (blockIdx.x * 4 + wave) * 16;
    if (node_base >= N_NODES) return;
    int nodec = min(node_base + m, N_NODES - 1);

    bf16x8 ahi[8], alo[8];
    {
        const unsigned short* r1h = M1hi + (size_t)nodec * D + quad * 8;
        const unsigned short* r1l = M1lo + (size_t)nodec * D + quad * 8;
        const unsigned short* r2h = M2hi + (size_t)nodec * D + quad * 8;
        const unsigned short* r2l = M2lo + (size_t)nodec * D + quad * 8;
        #pragma unroll
        for (int ks = 0; ks < 4; ks++) {
            ahi[ks]     = *(const bf16x8*)(r1h + ks * 32);
            ahi[4 + ks] = *(const bf16x8*)(r2h + ks * 32);
            alo[ks]     = *(const bf16x8*)(r1l + ks * 32);
            alo[4 + ks] = *(const bf16x8*)(r2l + ks * 32);
        }
    }

    float res[3][4];
    #pragma unroll
    for (int nt = 0; nt < 3; nt++) {
        int f = nt * 16 + m;
        const unsigned short* whirow = Whi + (size_t)f * 256 + quad * 8;
        const unsigned short* wlorow = Wlo + (size_t)f * 256 + quad * 8;
        f32x4 acc = {0.f, 0.f, 0.f, 0.f};
        #pragma unroll
        for (int ks = 0; ks < 8; ks++) {
            bf16x8 bh = *(const bf16x8*)(whirow + ks * 32);
            bf16x8 bl = *(const bf16x8*)(wlorow + ks * 32);
            acc = __builtin_amdgcn_mfma_f32_16x16x32_bf16(ahi[ks], bh, acc, 0, 0, 0);
            acc = __builtin_amdgcn_mfma_f32_16x16x32_bf16(ahi[ks], bl, acc, 0, 0, 0);
            acc = __builtin_amdgcn_mfma_f32_16x16x32_bf16(alo[ks], bh, acc, 0, 0, 0);
        }
        float bv = (f < 40) ? bias[f] : 0.f;
        #pragma unroll
        for (int r = 0; r < 4; r++) res[nt][r] = acc[r] + bv;
    }

    #pragma unroll
    for (int r = 0; r < 4; r++) {
        float pm = -INFINITY;
        #pragma unroll
        for (int nt = 0; nt < 3; nt++)
            if (nt * 16 + m < 40) pm = fmaxf(pm, res[nt][r]);
        #pragma unroll
        for (int o = 8; o > 0; o >>= 1) pm = fmaxf(pm, __shfl_xor(pm, o, 64));
        float ps = 0.f;
        #pragma unroll
        for (int nt = 0; nt < 3; nt++)
            if (nt * 16 + m < 40) ps += expf(res[nt][r] - pm);
        #pragma unroll
        for (int o = 8; o > 0; o >>= 1) ps += __shfl_xor(ps, o, 64);
        float lse = pm + logf(ps);
        int nrow = node_base + quad * 4 + r;
        if (nrow >= N_NODES) continue;
        #pragma unroll
        for (int nt = 0; nt < 3; nt++) {
            int f = nt * 16 + m;
            if (f < 40) out[(size_t)nrow * 40 + f] = res[nt][r] - lse;
        }
    }
}

extern "C" void kernel_launch(void* const* d_in, const int* in_sizes, int n_in,
                              void* d_out, int out_size, void* d_ws, size_t ws_size,
                              hipStream_t stream) {
    const float* x     = (const float*)d_in[0];
    const int*   ei    = (const int*)d_in[1];
    const int*   src   = ei;
    const int*   dst   = ei + N_EDGES;
    const float* W1_l  = (const float*)d_in[2];
    const float* b1_l  = (const float*)d_in[3];
    const float* W1_r  = (const float*)d_in[4];
    const float* W2_l  = (const float*)d_in[5];
    const float* b2_l  = (const float*)d_in[6];
    const float* W2_r  = (const float*)d_in[7];
    const float* W_lin = (const float*)d_in[8];
    const float* b_lin = (const float*)d_in[9];
    float* out = (float*)d_out;

    const size_t nd = (size_t)N_NODES * D;
    unsigned short* xhi  = (unsigned short*)d_ws;    // aliased: h2hi after layer 2
    unsigned short* xlo  = xhi + nd;                 // aliased: h2lo
    unsigned short* h1hi = xlo + nd;
    unsigned short* h1lo = h1hi + nd;
    unsigned short* h2hi = xhi, *h2lo = xlo;
    unsigned short* W1hi = h1lo + nd;                // 128*256 bf16 each
    unsigned short* W1lo = W1hi + 128 * 256;
    unsigned short* W2hi = W1lo + 128 * 256;
    unsigned short* W2lo = W2hi + 128 * 256;
    unsigned short* WLhi = W2lo + 128 * 256;         // 48*256
    unsigned short* WLlo = WLhi + 48 * 256;
    int* deg    = (int*)(WLlo + 48 * 256);
    int* rowptr = deg + N_NODES;
    int* cursor = rowptr + N_NODES + 1;
    int* srcs_sorted = cursor + N_NODES;
    int* bsum   = srcs_sorted + N_EDGES;             // NBLK ints
    int* boff   = bsum + NBLK;                       // NBLK ints

    // ---- CSR build ----
    hipMemsetAsync(deg, 0, N_NODES * sizeof(int), stream);
    deg_kernel<<<(N_EDGES + 255) / 256, 256, 0, stream>>>(dst, deg);
    scan_block_sums<<<NBLK, 256, 0, stream>>>(deg, bsum);
    scan_offsets<<<1, 256, 0, stream>>>(bsum, boff);
    scan_write<<<NBLK, 256, 0, stream>>>(deg, boff, rowptr, cursor);
    bucket_kernel<<<(N_EDGES + 255) / 256, 256, 0, stream>>>(src, dst, cursor, srcs_sorted);

    // ---- casts / splits ----
    split_x_kernel<<<(N_NODES * D / 4 + 255) / 256, 256, 0, stream>>>(x, xhi, xlo, N_NODES * D);
    cast_cat_kernel<<<128, 128, 0, stream>>>(W1_l, W1_r, W1hi, W1lo);
    cast_cat_kernel<<<128, 128, 0, stream>>>(W2_l, W2_r, W2hi, W2lo);
    cast_wlin_kernel<<<48, 256, 0, stream>>>(W_lin, WLhi, WLlo);

    const int lblk = (N_NODES + 63) / 64;   // fused layers: 64 nodes/block
    const int fblk = (N_NODES + 63) / 64;   // final GEMM

    // ---- layer 1: gather(x) + GEMM -> h1 planes ----
    fused_layer<<<lblk, 512, 0, stream>>>(srcs_sorted, rowptr, xhi, xhi, xlo,
                                          W1hi, W1lo, b1_l, h1hi, h1lo);
    // ---- layer 2: gather(h1) + GEMM -> h2 planes (alias x planes; x dead) ----
    fused_layer<<<lblk, 512, 0, stream>>>(srcs_sorted, rowptr, h1hi, h1hi, h1lo,
                                          W2hi, W2lo, b2_l, h2hi, h2lo);

    // ---- final linear + fused log_softmax ----
    mfma_final_p<<<fblk, 256, 0, stream>>>(h1hi, h1lo, h2hi, h2lo, WLhi, WLlo, b_lin, out);
}